// Round 7
// baseline (362.767 us; speedup 1.0000x reference)
//
#include <hip/hip_runtime.h>
#include <stdint.h>

#define S_LEN 2048
#define D_MODEL 1024
#define N_HEAD 16
#define D_HEAD 64
#define N_BATCH 2
#define M_TOK (N_BATCH * S_LEN)  // 4096

typedef unsigned short u16;
typedef unsigned int u32;
typedef __attribute__((ext_vector_type(8))) short bf16x8;
typedef __attribute__((ext_vector_type(4))) short s16x4;
typedef __attribute__((ext_vector_type(4))) float f32x4;
typedef __attribute__((ext_vector_type(4))) unsigned short u16x4;

#define MFMA16(a, b, c) __builtin_amdgcn_mfma_f32_16x16x32_bf16((a), (b), (c), 0, 0, 0)

#if defined(__has_builtin)
#if __has_builtin(__builtin_amdgcn_mfma_f32_16x16x16bf16_1k)
#define HAVE_MFMA_16x16x16 1
#define MFMA_PV(a, b, c) __builtin_amdgcn_mfma_f32_16x16x16bf16_1k((a), (b), (c), 0, 0, 0)
#endif
#endif

#define WAITCNT(n) asm volatile("s_waitcnt vmcnt(" #n ")" ::: "memory")

__device__ __forceinline__ u16 f2bf(float f) {
  unsigned int u = __float_as_uint(f);
  u = (u + 0x7FFFu + ((u >> 16) & 1u)) >> 16;
  return (u16)u;
}

__device__ __forceinline__ void gload_lds16(const u16* g, u16* l) {
  __builtin_amdgcn_global_load_lds((const __attribute__((address_space(1))) void*)g,
                                   (__attribute__((address_space(3))) void*)l, 16, 0, 0);
}

// ---------------- fp32 -> bf16 convert, all 7 tensors in one launch ----------------
#define N4BIG (M_TOK * D_MODEL / 4)     // 1048576
#define N4W (D_MODEL * D_MODEL / 4)     // 262144
__global__ __launch_bounds__(256) void cvt7_kernel(
    const float* __restrict__ sk, const float* __restrict__ sv, const float* __restrict__ sq,
    const float* __restrict__ swq, const float* __restrict__ swk, const float* __restrict__ swv,
    const float* __restrict__ swo, u16* __restrict__ dk, u16* __restrict__ dv, u16* __restrict__ dq,
    u16* __restrict__ dwq, u16* __restrict__ dwk, u16* __restrict__ dwv, u16* __restrict__ dwo) {
  const float* s;
  u16* d;
  int n4;
  switch (blockIdx.y) {
    case 0: s = sk; d = dk; n4 = N4BIG; break;
    case 1: s = sv; d = dv; n4 = N4BIG; break;
    case 2: s = sq; d = dq; n4 = N4BIG; break;
    case 3: s = swq; d = dwq; n4 = N4W; break;
    case 4: s = swk; d = dwk; n4 = N4W; break;
    case 5: s = swv; d = dwv; n4 = N4W; break;
    default: s = swo; d = dwo; n4 = N4W; break;
  }
  int i = blockIdx.x * blockDim.x + threadIdx.x;
  int stride = gridDim.x * blockDim.x;
  for (; i < n4; i += stride) {
    float4 v = ((const float4*)s)[i];
    u16x4 o = {f2bf(v.x), f2bf(v.y), f2bf(v.z), f2bf(v.w)};
    ((u16x4*)d)[i] = o;
  }
}

// ---------------- mask bit-pack: int32[4096][2048] -> u64[4096][32] -----------------
__global__ __launch_bounds__(256) void pack_mask(const int* __restrict__ mask,
                                                 unsigned long long* __restrict__ packed) {
  int wid = (blockIdx.x * blockDim.x + threadIdx.x) >> 6;
  int lane = threadIdx.x & 63;
  int nw = (gridDim.x * blockDim.x) >> 6;
  const int NW64 = M_TOK * (S_LEN / 64);  // 131072
  for (int widx = wid; widx < NW64; widx += nw) {
    int m = mask[(size_t)widx * 64 + lane];
    unsigned long long bits = __ballot(m != 0);
    if (lane == 0) packed[widx] = bits;
  }
}

// ---------------- GEMM body: C[M,N] = A[M,K]@Bw[N,K]^T, +bias, *scale ----------------
// m97 structure. outmode: 0 = bf16 row-major, 1 = fp32 row-major, 2 = bf16 [b][h][dh][s]
__device__ __forceinline__ void gemm_body(const u16* __restrict__ A, const u16* __restrict__ Bw,
                                          const float* __restrict__ bias, void* __restrict__ Cout,
                                          float scale, int outmode) {
  __shared__ u16 As[128 * 32];
  __shared__ u16 Bs[128 * 32];
  const int K = D_MODEL, N = D_MODEL;
  int tid = threadIdx.x;
  int w = tid >> 6, lane = tid & 63, lg = lane >> 4, lr = lane & 15;
  int m0 = blockIdx.x * 128, n0 = blockIdx.y * 128;
  int wr = w >> 1, wc = w & 1;
  f32x4 acc[4][4] = {};
  int r0 = tid >> 2;
  int r1 = 64 + (tid >> 2);
  int kk0 = (tid & 3) * 8;
  for (int kb = 0; kb < K; kb += 32) {
    gload_lds16(A + (size_t)(m0 + r0) * K + kb + kk0, As + w * 512);
    gload_lds16(A + (size_t)(m0 + r1) * K + kb + kk0, As + 2048 + w * 512);
    gload_lds16(Bw + (size_t)(n0 + r0) * K + kb + kk0, Bs + w * 512);
    gload_lds16(Bw + (size_t)(n0 + r1) * K + kb + kk0, Bs + 2048 + w * 512);
    __syncthreads();
    bf16x8 af[4], bfr[4];
#pragma unroll
    for (int i = 0; i < 4; i++)
      af[i] = *(const bf16x8*)(As + (wr * 64 + i * 16 + lr) * 32 + lg * 8);
#pragma unroll
    for (int i = 0; i < 4; i++)
      bfr[i] = *(const bf16x8*)(Bs + (wc * 64 + i * 16 + lr) * 32 + lg * 8);
#pragma unroll
    for (int mi = 0; mi < 4; mi++)
#pragma unroll
      for (int ni = 0; ni < 4; ni++)
        acc[mi][ni] = MFMA16(af[mi], bfr[ni], acc[mi][ni]);
    __syncthreads();
  }
#pragma unroll
  for (int mi = 0; mi < 4; mi++)
#pragma unroll
    for (int ni = 0; ni < 4; ni++) {
      int col = n0 + wc * 64 + ni * 16 + lr;
      float bv = bias[col];
      if (outmode == 2) {
        int row0 = m0 + wr * 64 + mi * 16 + lg * 4;
        int bb = row0 >> 11, ss = row0 & (S_LEN - 1);
        u16x4 pk;
#pragma unroll
        for (int r = 0; r < 4; r++) pk[r] = f2bf((acc[mi][ni][r] + bv) * scale);
        *(u16x4*)((u16*)Cout + ((size_t)((bb * N_HEAD + (col >> 6)) * D_HEAD + (col & 63)) * S_LEN + ss)) = pk;
      } else {
#pragma unroll
        for (int r = 0; r < 4; r++) {
          int row = m0 + wr * 64 + mi * 16 + lg * 4 + r;
          float v = (acc[mi][ni][r] + bv) * scale;
          if (outmode == 1)
            ((float*)Cout)[(size_t)row * N + col] = v;
          else
            ((u16*)Cout)[(size_t)row * N + col] = f2bf(v);
        }
      }
    }
}

// Q scale folds 1/sqrt(64) * log2(e) so attention uses exp2 directly.
#define QSCALE 0.18033688011112042f

__global__ __launch_bounds__(256) void proj3_kernel(
    const u16* __restrict__ kbf, const u16* __restrict__ vbf, const u16* __restrict__ qbf,
    const u16* __restrict__ wkb, const u16* __restrict__ wvb, const u16* __restrict__ wqb,
    const float* __restrict__ bk, const float* __restrict__ bv, const float* __restrict__ bq,
    u16* __restrict__ kup, u16* __restrict__ vtg, u16* __restrict__ qup) {
  int z = blockIdx.z;
  if (z == 0)
    gemm_body(kbf, wkb, bk, kup, 1.0f, 0);
  else if (z == 1)
    gemm_body(vbf, wvb, bv, vtg, 1.0f, 2);
  else
    gemm_body(qbf, wqb, bq, qup, QSCALE, 0);
}

__global__ __launch_bounds__(256) void gemm_out_kernel(const u16* __restrict__ A,
                                                       const u16* __restrict__ Bw,
                                                       const float* __restrict__ bias,
                                                       float* __restrict__ C) {
  gemm_body(A, Bw, bias, C, 1.0f, 1);
}

// ---------------- fused attention: KVBLK=64, quad-buffer, 1 barrier/tile ------------
// grid = 512 flat blocks (XCD-chunk swizzled), 512 threads = 8 waves. Wave w owns
// q-rows [q0+16w, +16), full k. Tiles: K [64 k][64 dh] (8KB), V^T [64 dh][64 k] (8KB),
// 4 buffers each, 2-deep prefetch, mask bits pipelined 1 tile ahead in regs (ping-pong
// mA/mB via 4x unroll). Exact vmcnt ledger; attn stores never explicitly drained.
__global__ __launch_bounds__(512, 4) void attn_kernel(
    const u16* __restrict__ Qup, const u16* __restrict__ Kup, const u16* __restrict__ Vt,
    const u32* __restrict__ mpack, float* __restrict__ attn_out, u16* __restrict__ ctx) {
  __shared__ u16 kbuf[4][64 * 64];
  __shared__ u16 vbuf[4][64 * 64];
#if !defined(HAVE_MFMA_16x16x16)
  __shared__ u16 pbuf[8][16 * 64];
#endif
  int tid = threadIdx.x;
  int w = tid >> 6, lane = tid & 63, lg = lane >> 4, lr = lane & 15;

  // XCD-chunked bijective swizzle (512 % 8 == 0)
  int fb = blockIdx.x;
  int logical = (fb & 7) * 64 + (fb >> 3);
  int qx = logical & 15;
  int h = (logical >> 4) & 15;
  int b = logical >> 8;
  int q0 = qx * 128;
  int q = q0 + w * 16 + lr;
  const float NEGV = -100000000.0f;

  bf16x8 qf0, qf1;
  {
    const u16* qrow = Qup + (size_t)(b * S_LEN + q) * D_MODEL + h * D_HEAD;
    qf0 = *(const bf16x8*)(qrow + lg * 8);
    qf1 = *(const bf16x8*)(qrow + 32 + lg * 8);
  }
  const u16* Kb = Kup + (size_t)(b * S_LEN) * D_MODEL + h * D_HEAD;
  const u16* Vb = Vt + (size_t)(b * N_HEAD + h) * D_HEAD * S_LEN;
  const u32* mrow = mpack + (size_t)(b * S_LEN + q) * (S_LEN / 32);
  float* attn_b = attn_out + ((size_t)(b * N_HEAD + h) * S_LEN + q) * S_LEN;

  // staging: thread -> (row = tid>>3, chunk = (tid&7)^(row&7)); LDS dest linear.
  int srow = tid >> 3;
  int schunk = (tid & 7) ^ (srow & 7);
  const u16* KgA = Kb + (size_t)srow * D_MODEL + schunk * 8;  // + kt*64*D_MODEL
  const u16* VgA = Vb + (size_t)srow * S_LEN + schunk * 8;    // + kt*64
  const int sw = lr & 7;  // read-side swizzle key (frag rows have row&7 == lr&7)

#define STAGE_K(bn, ktn) gload_lds16(KgA + (size_t)(ktn) * 64 * D_MODEL, &kbuf[bn][w * 512])
#define STAGE_V(bn, ktn) gload_lds16(VgA + (size_t)(ktn) * 64, &vbuf[bn][w * 512])
#define BARRIER()                      \
  __builtin_amdgcn_s_barrier();        \
  __builtin_amdgcn_sched_barrier(0)
#define SEAL() __builtin_amdgcn_sched_barrier(0)

  // ================= pass 0: row sums =================
  float lsA = 0.f, lsB = 0.f;

#define P0_BODY(KT, MMU)                                                   \
  {                                                                        \
    const u16* kc = &kbuf[(KT) & 3][0];                                    \
    _Pragma("unroll") for (int t = 0; t < 4; t++) {                        \
      const u16* kr = kc + (t * 16 + lr) * 64;                             \
      bf16x8 k0 = *(const bf16x8*)(kr + ((lg ^ sw) << 3));                 \
      bf16x8 k1 = *(const bf16x8*)(kr + (((lg + 4) ^ sw) << 3));           \
      f32x4 a = {0.f, 0.f, 0.f, 0.f};                                      \
      a = MFMA16(k0, qf0, a);                                              \
      a = MFMA16(k1, qf1, a);                                              \
      u32 wbits = (t < 2) ? (MMU).x : (MMU).y;                             \
      _Pragma("unroll") for (int r = 0; r < 4; r++) {                      \
        int j = (t * 16 + lg * 4 + r) & 31;                                \
        float s = ((wbits >> j) & 1u) ? NEGV : a[r];                       \
        if (r & 1) lsB += exp2f(s); else lsA += exp2f(s);                  \
      }                                                                    \
    }                                                                      \
  }

#define P0_FULL(KT, MMU, MML, WN)                          \
  do {                                                     \
    MML = *(const uint2*)(mrow + ((KT) + 1) * 2);          \
    STAGE_K(((KT) + 2) & 3, (KT) + 2);                     \
    WAITCNT(WN);                                           \
    BARRIER();                                             \
    P0_BODY(KT, MMU);                                      \
    SEAL();                                                \
  } while (0)
#define P0_NOST(KT, MMU, MML, WN)                          \
  do {                                                     \
    MML = *(const uint2*)(mrow + ((KT) + 1) * 2);          \
    WAITCNT(WN);                                           \
    BARRIER();                                             \
    P0_BODY(KT, MMU);                                      \
    SEAL();                                                \
  } while (0)
#define P0_LAST(KT, MMU, WN)                               \
  do {                                                     \
    WAITCNT(WN);                                           \
    BARRIER();                                             \
    P0_BODY(KT, MMU);                                      \
    SEAL();                                                \
  } while (0)

  uint2 mA, mB;
  mA = *(const uint2*)(mrow);
  STAGE_K(0, 0);
  STAGE_K(1, 1);
  P0_FULL(0, mA, mB, 3);
  P0_FULL(1, mB, mA, 3);
  P0_FULL(2, mA, mB, 3);
  P0_FULL(3, mB, mA, 3);
  for (int m = 1; m < 7; m++) {
    const int b4 = m * 4;
    P0_FULL(b4 + 0, mA, mB, 3);
    P0_FULL(b4 + 1, mB, mA, 3);
    P0_FULL(b4 + 2, mA, mB, 3);
    P0_FULL(b4 + 3, mB, mA, 3);
  }
  P0_FULL(28, mA, mB, 3);
  P0_FULL(29, mB, mA, 3);
  P0_NOST(30, mA, mB, 2);
  P0_LAST(31, mB, 0);

  float lsum = lsA + lsB;
  lsum += __shfl_xor(lsum, 16);
  lsum += __shfl_xor(lsum, 32);
  float inv_l = lsum > 0.f ? 1.0f / lsum : 0.f;

  // ================= pass 1: normalize, write attn, PV =================
  f32x4 ctxacc[4] = {};

#if defined(HAVE_MFMA_16x16x16)
#define P1_BODY(KT, MMU)                                                   \
  {                                                                        \
    const u16* kc = &kbuf[(KT) & 3][0];                                    \
    const u16* vc = &vbuf[(KT) & 3][0];                                    \
    _Pragma("unroll") for (int t = 0; t < 4; t++) {                        \
      const u16* kr = kc + (t * 16 + lr) * 64;                             \
      bf16x8 k0 = *(const bf16x8*)(kr + ((lg ^ sw) << 3));                 \
      bf16x8 k1 = *(const bf16x8*)(kr + (((lg + 4) ^ sw) << 3));           \
      f32x4 a = {0.f, 0.f, 0.f, 0.f};                                      \
      a = MFMA16(k0, qf0, a);                                              \
      a = MFMA16(k1, qf1, a);                                              \
      u32 wbits = (t < 2) ? (MMU).x : (MMU).y;                             \
      f32x4 p;                                                             \
      u16x4 pb;                                                            \
      _Pragma("unroll") for (int r = 0; r < 4; r++) {                      \
        int j = (t * 16 + lg * 4 + r) & 31;                                \
        float s = ((wbits >> j) & 1u) ? NEGV : a[r];                       \
        float pv = exp2f(s) * inv_l;                                       \
        p[r] = pv;                                                         \
        pb[r] = f2bf(pv);                                                  \
      }                                                                    \
      *(f32x4*)(attn_b + (KT) * 64 + t * 16 + lg * 4) = p;                 \
      s16x4 ap = {(short)pb[0], (short)pb[1], (short)pb[2], (short)pb[3]}; \
      _Pragma("unroll") for (int d = 0; d < 4; d++) {                      \
        s16x4 vf = *(const s16x4*)(vc + (d * 16 + lr) * 64 +               \
                                   (((t * 2 + (lg >> 1)) ^ sw) << 3) +     \
                                   ((lg & 1) << 2));                       \
        ctxacc[d] = MFMA_PV(ap, vf, ctxacc[d]);                            \
      }                                                                    \
    }                                                                      \
  }
#else
#define P1_BODY(KT, MMU)                                                   \
  {                                                                        \
    const u16* kc = &kbuf[(KT) & 3][0];                                    \
    const u16* vc = &vbuf[(KT) & 3][0];                                    \
    u16* pw = &pbuf[w][0];                                                 \
    _Pragma("unroll") for (int t = 0; t < 4; t++) {                        \
      const u16* kr = kc + (t * 16 + lr) * 64;                             \
      bf16x8 k0 = *(const bf16x8*)(kr + ((lg ^ sw) << 3));                 \
      bf16x8 k1 = *(const bf16x8*)(kr + (((lg + 4) ^ sw) << 3));           \
      f32x4 a = {0.f, 0.f, 0.f, 0.f};                                      \
      a = MFMA16(k0, qf0, a);                                              \
      a = MFMA16(k1, qf1, a);                                              \
      u32 wbits = (t < 2) ? (MMU).x : (MMU).y;                             \
      f32x4 p;                                                             \
      u16x4 pb;                                                            \
      _Pragma("unroll") for (int r = 0; r < 4; r++) {                      \
        int j = (t * 16 + lg * 4 + r) & 31;                                \
        float s = ((wbits >> j) & 1u) ? NEGV : a[r];                       \
        float pv = exp2f(s) * inv_l;                                       \
        p[r] = pv;                                                         \
        pb[r] = f2bf(pv);                                                  \
      }                                                                    \
      *(f32x4*)(attn_b + (KT) * 64 + t * 16 + lg * 4) = p;                 \
      *(u16x4*)(pw + lr * 64 + (((t * 2 + (lg >> 1)) ^ sw) << 3) +         \
                ((lg & 1) << 2)) = pb;                                     \
    }                                                                      \
    bf16x8 pa0 = *(const bf16x8*)(pw + lr * 64 + ((lg ^ sw) << 3));        \
    bf16x8 pa1 = *(const bf16x8*)(pw + lr * 64 + (((lg + 4) ^ sw) << 3));  \
    _Pragma("unroll") for (int d = 0; d < 4; d++) {                        \
      const u16* vr = vc + (d * 16 + lr) * 64;                             \
      bf16x8 v0 = *(const bf16x8*)(vr + ((lg ^ sw) << 3));                 \
      bf16x8 v1 = *(const bf16x8*)(vr + (((lg + 4) ^ sw) << 3));           \
      ctxacc[d] = MFMA16(pa0, v0, ctxacc[d]);                              \
      ctxacc[d] = MFMA16(pa1, v1, ctxacc[d]);                              \
    }                                                                      \
  }
#endif

#define P1_FULL(KT, MMU, MML, WN)                          \
  do {                                                     \
    MML = *(const uint2*)(mrow + ((KT) + 1) * 2);          \
    STAGE_K(((KT) + 2) & 3, (KT) + 2);                     \
    STAGE_V(((KT) + 2) & 3, (KT) + 2);                     \
    WAITCNT(WN);                                           \
    BARRIER();                                             \
    P1_BODY(KT, MMU);                                      \
    SEAL();                                                \
  } while (0)
#define P1_NOST(KT, MMU, MML, WN)                          \
  do {                                                     \
    MML = *(const uint2*)(mrow + ((KT) + 1) * 2);          \
    WAITCNT(WN);                                           \
    BARRIER();                                             \
    P1_BODY(KT, MMU);                                      \
    SEAL();                                                \
  } while (0)
#define P1_LAST(KT, MMU, WN)                               \
  do {                                                     \
    WAITCNT(WN);                                           \
    BARRIER();                                             \
    P1_BODY(KT, MMU);                                      \
    SEAL();                                                \
  } while (0)

  mA = *(const uint2*)(mrow);
  STAGE_K(0, 0);
  STAGE_V(0, 0);
  STAGE_K(1, 1);
  STAGE_V(1, 1);
  P1_FULL(0, mA, mB, 5);
  P1_FULL(1, mB, mA, 9);
  P1_FULL(2, mA, mB, 9);
  P1_FULL(3, mB, mA, 9);
  for (int m = 1; m < 7; m++) {
    const int b4 = m * 4;
    P1_FULL(b4 + 0, mA, mB, 9);
    P1_FULL(b4 + 1, mB, mA, 9);
    P1_FULL(b4 + 2, mA, mB, 9);
    P1_FULL(b4 + 3, mB, mA, 9);
  }
  P1_FULL(28, mA, mB, 9);
  P1_FULL(29, mB, mA, 9);
  P1_NOST(30, mA, mB, 7);
  P1_LAST(31, mB, 4);

  // context out: [B,S,H,DH] == [M_TOK, D_MODEL] row-major
#pragma unroll
  for (int d = 0; d < 4; d++)
#pragma unroll
    for (int r = 0; r < 4; r++) {
      int sq = q0 + w * 16 + lg * 4 + r;
      ctx[(size_t)(b * S_LEN + sq) * D_MODEL + h * D_HEAD + d * 16 + lr] = f2bf(ctxacc[d][r]);
    }
#undef STAGE_K
#undef STAGE_V
#undef BARRIER
#undef SEAL
#undef P0_BODY
#undef P0_FULL
#undef P0_NOST
#undef P0_LAST
#undef P1_BODY
#undef P1_FULL
#undef P1_NOST
#undef P1_LAST
}

// ---------------- workspace layout (u16 units) ----------------
#define O_KBF 0u          // bf16 key input; reused for packed mask after projections
#define O_VBF 4194304u
#define O_QBF 8388608u
#define O_WQ 12582912u
#define O_WK 13631488u
#define O_WV 14680064u
#define O_WO 15728640u
#define O_QUP 16777216u
#define O_KUP 20971520u
#define O_VUP 25165824u   // V head-transposed [b][h][dh][s]
#define O_CTX 29360128u
// total = 33554432 u16 = 64 MiB

extern "C" void kernel_launch(void* const* d_in, const int* in_sizes, int n_in,
                              void* d_out, int out_size, void* d_ws, size_t ws_size,
                              hipStream_t stream) {
  const float* key = (const float*)d_in[0];
  const float* value = (const float*)d_in[1];
  const float* query = (const float*)d_in[2];
  const int* mask = (const int*)d_in[3];
  const float* Wq = (const float*)d_in[4];
  const float* bq = (const float*)d_in[5];
  const float* Wk = (const float*)d_in[6];
  const float* bk = (const float*)d_in[7];
  const float* Wv = (const float*)d_in[8];
  const float* bv = (const float*)d_in[9];
  const float* Wo = (const float*)d_in[10];
  const float* bo = (const float*)d_in[11];

  u16* ws = (u16*)d_ws;
  u16* kbf = ws + O_KBF;
  u16* vbf = ws + O_VBF;
  u16* qbf = ws + O_QBF;
  u16* wqb = ws + O_WQ;
  u16* wkb = ws + O_WK;
  u16* wvb = ws + O_WV;
  u16* wob = ws + O_WO;
  u16* qup = ws + O_QUP;
  u16* kup = ws + O_KUP;
  u16* vtg = ws + O_VUP;
  u16* ctxb = ws + O_CTX;

  float* out = (float*)d_out;
  float* attn = out + (size_t)N_BATCH * S_LEN * D_MODEL;

  cvt7_kernel<<<dim3(512, 7), 256, 0, stream>>>(key, value, query, Wq, Wk, Wv, Wo, kbf, vbf, qbf,
                                                wqb, wkb, wvb, wob);
  proj3_kernel<<<dim3(32, 8, 3), 256, 0, stream>>>(kbf, vbf, qbf, wkb, wvb, wqb, bk, bv, bq, kup,
                                                   vtg, qup);
  pack_mask<<<1024, 256, 0, stream>>>(mask, (unsigned long long*)kbf);
  attn_kernel<<<512, 512, 0, stream>>>(qup, kup, vtg, (const u32*)kbf, attn, ctxb);
  gemm_out_kernel<<<dim3(32, 8), 256, 0, stream>>>(ctxb, wob, bo, out);
}

// Round 8
// 330.615 us; speedup vs baseline: 1.0972x; 1.0972x over previous
//
#include <hip/hip_runtime.h>
#include <stdint.h>

#define S_LEN 2048
#define D_MODEL 1024
#define N_HEAD 16
#define D_HEAD 64
#define N_BATCH 2
#define M_TOK (N_BATCH * S_LEN)  // 4096

typedef unsigned short u16;
typedef unsigned int u32;
typedef __attribute__((ext_vector_type(8))) short bf16x8;
typedef __attribute__((ext_vector_type(4))) short s16x4;
typedef __attribute__((ext_vector_type(4))) float f32x4;
typedef __attribute__((ext_vector_type(4))) unsigned short u16x4;

#define MFMA16(a, b, c) __builtin_amdgcn_mfma_f32_16x16x32_bf16((a), (b), (c), 0, 0, 0)

#if defined(__has_builtin)
#if __has_builtin(__builtin_amdgcn_mfma_f32_16x16x16bf16_1k)
#define HAVE_MFMA_16x16x16 1
#define MFMA_PV(a, b, c) __builtin_amdgcn_mfma_f32_16x16x16bf16_1k((a), (b), (c), 0, 0, 0)
#endif
#endif

#define WAITCNT(n) asm volatile("s_waitcnt vmcnt(" #n ")" ::: "memory")
#define BAR() __builtin_amdgcn_s_barrier()

__device__ __forceinline__ u16 f2bf(float f) {
  unsigned int u = __float_as_uint(f);
  u = (u + 0x7FFFu + ((u >> 16) & 1u)) >> 16;
  return (u16)u;
}

__device__ __forceinline__ void gload_lds16(const u16* g, u16* l) {
  __builtin_amdgcn_global_load_lds((const __attribute__((address_space(1))) void*)g,
                                   (__attribute__((address_space(3))) void*)l, 16, 0, 0);
}

// ---------------- fp32 -> bf16 convert, all 7 tensors in one launch ----------------
#define N4BIG (M_TOK * D_MODEL / 4)     // 1048576
#define N4W (D_MODEL * D_MODEL / 4)     // 262144
__global__ __launch_bounds__(256) void cvt7_kernel(
    const float* __restrict__ sk, const float* __restrict__ sv, const float* __restrict__ sq,
    const float* __restrict__ swq, const float* __restrict__ swk, const float* __restrict__ swv,
    const float* __restrict__ swo, u16* __restrict__ dk, u16* __restrict__ dv, u16* __restrict__ dq,
    u16* __restrict__ dwq, u16* __restrict__ dwk, u16* __restrict__ dwv, u16* __restrict__ dwo) {
  const float* s;
  u16* d;
  int n4;
  switch (blockIdx.y) {
    case 0: s = sk; d = dk; n4 = N4BIG; break;
    case 1: s = sv; d = dv; n4 = N4BIG; break;
    case 2: s = sq; d = dq; n4 = N4BIG; break;
    case 3: s = swq; d = dwq; n4 = N4W; break;
    case 4: s = swk; d = dwk; n4 = N4W; break;
    case 5: s = swv; d = dwv; n4 = N4W; break;
    default: s = swo; d = dwo; n4 = N4W; break;
  }
  int i = blockIdx.x * blockDim.x + threadIdx.x;
  int stride = gridDim.x * blockDim.x;
  for (; i < n4; i += stride) {
    float4 v = ((const float4*)s)[i];
    u16x4 o = {f2bf(v.x), f2bf(v.y), f2bf(v.z), f2bf(v.w)};
    ((u16x4*)d)[i] = o;
  }
}

// ---------------- mask bit-pack: int32[4096][2048] -> u64[4096][32] -----------------
__global__ __launch_bounds__(256) void pack_mask(const int* __restrict__ mask,
                                                 unsigned long long* __restrict__ packed) {
  int wid = (blockIdx.x * blockDim.x + threadIdx.x) >> 6;
  int lane = threadIdx.x & 63;
  int nw = (gridDim.x * blockDim.x) >> 6;
  const int NW64 = M_TOK * (S_LEN / 64);  // 131072
  for (int widx = wid; widx < NW64; widx += nw) {
    int m = mask[(size_t)widx * 64 + lane];
    unsigned long long bits = __ballot(m != 0);
    if (lane == 0) packed[widx] = bits;
  }
}

// ---------------- GEMM body: C[M,N] = A[M,K]@Bw[N,K]^T, +bias, *scale ----------------
// m97 structure. outmode: 0 = bf16 row-major, 1 = fp32 row-major, 2 = bf16 [b][h][dh][s]
__device__ __forceinline__ void gemm_body(const u16* __restrict__ A, const u16* __restrict__ Bw,
                                          const float* __restrict__ bias, void* __restrict__ Cout,
                                          float scale, int outmode) {
  __shared__ u16 As[128 * 32];
  __shared__ u16 Bs[128 * 32];
  const int K = D_MODEL, N = D_MODEL;
  int tid = threadIdx.x;
  int w = tid >> 6, lane = tid & 63, lg = lane >> 4, lr = lane & 15;
  int m0 = blockIdx.x * 128, n0 = blockIdx.y * 128;
  int wr = w >> 1, wc = w & 1;
  f32x4 acc[4][4] = {};
  int r0 = tid >> 2;
  int r1 = 64 + (tid >> 2);
  int kk0 = (tid & 3) * 8;
  for (int kb = 0; kb < K; kb += 32) {
    gload_lds16(A + (size_t)(m0 + r0) * K + kb + kk0, As + w * 512);
    gload_lds16(A + (size_t)(m0 + r1) * K + kb + kk0, As + 2048 + w * 512);
    gload_lds16(Bw + (size_t)(n0 + r0) * K + kb + kk0, Bs + w * 512);
    gload_lds16(Bw + (size_t)(n0 + r1) * K + kb + kk0, Bs + 2048 + w * 512);
    __syncthreads();
    bf16x8 af[4], bfr[4];
#pragma unroll
    for (int i = 0; i < 4; i++)
      af[i] = *(const bf16x8*)(As + (wr * 64 + i * 16 + lr) * 32 + lg * 8);
#pragma unroll
    for (int i = 0; i < 4; i++)
      bfr[i] = *(const bf16x8*)(Bs + (wc * 64 + i * 16 + lr) * 32 + lg * 8);
#pragma unroll
    for (int mi = 0; mi < 4; mi++)
#pragma unroll
      for (int ni = 0; ni < 4; ni++)
        acc[mi][ni] = MFMA16(af[mi], bfr[ni], acc[mi][ni]);
    __syncthreads();
  }
#pragma unroll
  for (int mi = 0; mi < 4; mi++)
#pragma unroll
    for (int ni = 0; ni < 4; ni++) {
      int col = n0 + wc * 64 + ni * 16 + lr;
      float bv = bias[col];
      if (outmode == 2) {
        int row0 = m0 + wr * 64 + mi * 16 + lg * 4;
        int bb = row0 >> 11, ss = row0 & (S_LEN - 1);
        u16x4 pk;
#pragma unroll
        for (int r = 0; r < 4; r++) pk[r] = f2bf((acc[mi][ni][r] + bv) * scale);
        *(u16x4*)((u16*)Cout + ((size_t)((bb * N_HEAD + (col >> 6)) * D_HEAD + (col & 63)) * S_LEN + ss)) = pk;
      } else {
#pragma unroll
        for (int r = 0; r < 4; r++) {
          int row = m0 + wr * 64 + mi * 16 + lg * 4 + r;
          float v = (acc[mi][ni][r] + bv) * scale;
          if (outmode == 1)
            ((float*)Cout)[(size_t)row * N + col] = v;
          else
            ((u16*)Cout)[(size_t)row * N + col] = f2bf(v);
        }
      }
    }
}

// Q scale folds 1/sqrt(64) * log2(e) so attention uses exp2 directly.
#define QSCALE 0.18033688011112042f

__global__ __launch_bounds__(256) void proj3_kernel(
    const u16* __restrict__ kbf, const u16* __restrict__ vbf, const u16* __restrict__ qbf,
    const u16* __restrict__ wkb, const u16* __restrict__ wvb, const u16* __restrict__ wqb,
    const float* __restrict__ bk, const float* __restrict__ bv, const float* __restrict__ bq,
    u16* __restrict__ kup, u16* __restrict__ vtg, u16* __restrict__ qup) {
  int z = blockIdx.z;
  if (z == 0)
    gemm_body(kbf, wkb, bk, kup, 1.0f, 0);
  else if (z == 1)
    gemm_body(vbf, wvb, bv, vtg, 1.0f, 2);
  else
    gemm_body(qbf, wqb, bq, qup, QSCALE, 0);
}

__global__ __launch_bounds__(256) void gemm_out_kernel(const u16* __restrict__ A,
                                                       const u16* __restrict__ Bw,
                                                       const float* __restrict__ bias,
                                                       float* __restrict__ C) {
  gemm_body(A, Bw, bias, C, 1.0f, 1);
}

// ---------------- fused attention: KVBLK=128, dbuf, mask pipelined ahead ------------
// grid = 512 flat blocks (XCD-chunk swizzled), 512 threads = 8 waves. Wave w owns
// q-rows [q0+16w, +16), full k. K tile [128 k][64 dh] (16KB, 2 gloads), V^T tile
// [64 dh][128 k] (16KB, 2 gloads), XOR-swizzled (chunk16B ^= row&7). Mask uint4 is
// loaded ONE TILE AHEAD into ping-pong regs (mA/mB) so the consumed mask is always
// older than the in-flight prefetch -> compiler's auto-wait == our counted WAITCNT.
__global__ __launch_bounds__(512, 4) void attn_kernel(
    const u16* __restrict__ Qup, const u16* __restrict__ Kup, const u16* __restrict__ Vt,
    const u32* __restrict__ mpack, float* __restrict__ attn_out, u16* __restrict__ ctx) {
  __shared__ u16 kbuf[2][128 * 64];
  __shared__ u16 vbuf[2][64 * 128];
#if !defined(HAVE_MFMA_16x16x16)
  __shared__ u16 pbuf[8][16 * 64];
#endif
  int tid = threadIdx.x;
  int w = tid >> 6, lane = tid & 63, lg = lane >> 4, lr = lane & 15;

  // XCD-chunked bijective swizzle (512 % 8 == 0)
  int fb = blockIdx.x;
  int logical = (fb & 7) * 64 + (fb >> 3);
  int qx = logical & 15;
  int h = (logical >> 4) & 15;
  int b = logical >> 8;
  int q0 = qx * 128;
  int q = q0 + w * 16 + lr;
  const float NEGV = -100000000.0f;

  bf16x8 qf0, qf1;
  {
    const u16* qrow = Qup + (size_t)(b * S_LEN + q) * D_MODEL + h * D_HEAD;
    qf0 = *(const bf16x8*)(qrow + lg * 8);
    qf1 = *(const bf16x8*)(qrow + 32 + lg * 8);
  }
  const u16* Kb = Kup + (size_t)(b * S_LEN) * D_MODEL + h * D_HEAD;
  const u16* Vb = Vt + (size_t)(b * N_HEAD + h) * D_HEAD * S_LEN;
  const u32* mrow = mpack + (size_t)(b * S_LEN + q) * (S_LEN / 32);
  float* attn_b = attn_out + ((size_t)(b * N_HEAD + h) * S_LEN + q) * S_LEN;

  // staging: thread -> (row, chunk) with pre-swizzled global source; LDS dest linear.
  int krow = tid >> 3;                       // 0..63 (second gload: +64, same &7)
  int kchunk = (tid & 7) ^ (krow & 7);
  const u16* KgA = Kb + (size_t)krow * D_MODEL + kchunk * 8;
  int vrow = tid >> 4;                       // 0..31 (second gload: +32, same &7)
  int vchunk = (tid & 15) ^ (vrow & 7);
  const u16* VgA = Vb + (size_t)vrow * S_LEN + vchunk * 8;
  const int sw = lr & 7;                     // read-side swizzle key

#define STAGE_K(bn, ktn)                                                    \
  do {                                                                      \
    const u16* _s = KgA + (size_t)(ktn) * 128 * D_MODEL;                    \
    gload_lds16(_s, &kbuf[bn][0] + w * 512);                                \
    gload_lds16(_s + (size_t)64 * D_MODEL, &kbuf[bn][4096] + w * 512);      \
  } while (0)
#define STAGE_V(bn, ktn)                                                    \
  do {                                                                      \
    const u16* _s = VgA + (size_t)(ktn) * 128;                              \
    gload_lds16(_s, &vbuf[bn][0] + w * 512);                                \
    gload_lds16(_s + (size_t)32 * S_LEN, &vbuf[bn][4096] + w * 512);        \
  } while (0)

  // ================= pass 0: row sums =================
  float lsA = 0.f, lsB = 0.f;

#define P0_BODY(BN, MM)                                                     \
  {                                                                         \
    const u16* kc = &kbuf[BN][0];                                           \
    _Pragma("unroll") for (int t = 0; t < 8; t++) {                         \
      const u16* kr = kc + (t * 16 + lr) * 64;                              \
      bf16x8 k0 = *(const bf16x8*)(kr + ((lg ^ sw) << 3));                  \
      bf16x8 k1 = *(const bf16x8*)(kr + (((lg + 4) ^ sw) << 3));            \
      f32x4 a = {0.f, 0.f, 0.f, 0.f};                                       \
      a = MFMA16(k0, qf0, a);                                               \
      a = MFMA16(k1, qf1, a);                                               \
      u32 wbits = (t >> 1) == 0 ? (MM).x                                    \
                : (t >> 1) == 1 ? (MM).y                                    \
                : (t >> 1) == 2 ? (MM).z : (MM).w;                          \
      _Pragma("unroll") for (int r = 0; r < 4; r++) {                       \
        int j = (t * 16 + lg * 4 + r) & 31;                                 \
        float s = ((wbits >> j) & 1u) ? NEGV : a[r];                        \
        if (r & 1) lsB += exp2f(s); else lsA += exp2f(s);                   \
      }                                                                     \
    }                                                                       \
  }

  uint4 mA, mB;
  mA = *(const uint4*)(mrow);
  STAGE_K(0, 0);
  for (int it = 0; it < 7; it++) {
    int kt = it * 2;
    mB = *(const uint4*)(mrow + (kt + 1) * 4);
    STAGE_K(1, kt + 1);
    WAITCNT(3);
    BAR();
    P0_BODY(0, mA);
    BAR();
    mA = *(const uint4*)(mrow + (kt + 2) * 4);
    STAGE_K(0, kt + 2);
    WAITCNT(3);
    BAR();
    P0_BODY(1, mB);
    BAR();
  }
  // kt = 14
  mB = *(const uint4*)(mrow + 15 * 4);
  STAGE_K(1, 15);
  WAITCNT(3);
  BAR();
  P0_BODY(0, mA);
  BAR();
  // kt = 15
  WAITCNT(0);
  BAR();
  P0_BODY(1, mB);

  float lsum = lsA + lsB;
  lsum += __shfl_xor(lsum, 16);
  lsum += __shfl_xor(lsum, 32);
  // fold 1/lsum into the exponent: p = exp2(s + il2)
  float il2 = lsum > 0.f ? -__log2f(lsum) : 0.f;

  BAR();  // seal pass-0 buf reads before pass-1 staging overwrites

  // ================= pass 1: write attn, PV accumulate =================
  f32x4 ctxacc[4] = {};

#if defined(HAVE_MFMA_16x16x16)
#define P1_BODY(BN, MM, KT)                                                 \
  {                                                                         \
    const u16* kc = &kbuf[BN][0];                                           \
    const u16* vc = &vbuf[BN][0];                                           \
    _Pragma("unroll") for (int t = 0; t < 8; t++) {                         \
      const u16* kr = kc + (t * 16 + lr) * 64;                              \
      bf16x8 k0 = *(const bf16x8*)(kr + ((lg ^ sw) << 3));                  \
      bf16x8 k1 = *(const bf16x8*)(kr + (((lg + 4) ^ sw) << 3));            \
      f32x4 a = {0.f, 0.f, 0.f, 0.f};                                       \
      a = MFMA16(k0, qf0, a);                                                \
      a = MFMA16(k1, qf1, a);                                                \
      u32 wbits = (t >> 1) == 0 ? (MM).x                                    \
                : (t >> 1) == 1 ? (MM).y                                    \
                : (t >> 1) == 2 ? (MM).z : (MM).w;                          \
      f32x4 p;                                                              \
      u16x4 pb;                                                             \
      _Pragma("unroll") for (int r = 0; r < 4; r++) {                       \
        int j = (t * 16 + lg * 4 + r) & 31;                                 \
        float s = ((wbits >> j) & 1u) ? NEGV : (a[r] + il2);                \
        float pv = exp2f(s);                                                \
        p[r] = pv;                                                          \
        pb[r] = f2bf(pv);                                                   \
      }                                                                     \
      *(f32x4*)(attn_b + (KT) * 128 + t * 16 + lg * 4) = p;                 \
      s16x4 ap = {(short)pb[0], (short)pb[1], (short)pb[2], (short)pb[3]};  \
      _Pragma("unroll") for (int d = 0; d < 4; d++) {                       \
        s16x4 vf = *(const s16x4*)(vc + (d * 16 + lr) * 128 +               \
                                   (((t * 2 + (lg >> 1)) ^ sw) << 3) +      \
                                   ((lg & 1) << 2));                        \
        ctxacc[d] = MFMA_PV(ap, vf, ctxacc[d]);                             \
      }                                                                     \
    }                                                                       \
  }
#else
#define P1_BODY(BN, MM, KT)                                                 \
  {                                                                         \
    const u16* kc = &kbuf[BN][0];                                           \
    const u16* vc = &vbuf[BN][0];                                           \
    u16* pw = &pbuf[w][0];                                                  \
    _Pragma("unroll") for (int h2 = 0; h2 < 2; h2++) {                      \
      _Pragma("unroll") for (int tt = 0; tt < 4; tt++) {                    \
        const int t = h2 * 4 + tt;                                          \
        const u16* kr = kc + (t * 16 + lr) * 64;                            \
        bf16x8 k0 = *(const bf16x8*)(kr + ((lg ^ sw) << 3));                \
        bf16x8 k1 = *(const bf16x8*)(kr + (((lg + 4) ^ sw) << 3));          \
        f32x4 a = {0.f, 0.f, 0.f, 0.f};                                     \
        a = MFMA16(k0, qf0, a);                                              \
        a = MFMA16(k1, qf1, a);                                              \
        u32 wbits = (t >> 1) == 0 ? (MM).x                                  \
                  : (t >> 1) == 1 ? (MM).y                                  \
                  : (t >> 1) == 2 ? (MM).z : (MM).w;                        \
        f32x4 p;                                                            \
        u16x4 pb;                                                           \
        _Pragma("unroll") for (int r = 0; r < 4; r++) {                     \
          int j = (t * 16 + lg * 4 + r) & 31;                               \
          float s = ((wbits >> j) & 1u) ? NEGV : (a[r] + il2);              \
          float pv = exp2f(s);                                              \
          p[r] = pv;                                                        \
          pb[r] = f2bf(pv);                                                 \
        }                                                                   \
        *(f32x4*)(attn_b + (KT) * 128 + t * 16 + lg * 4) = p;               \
        *(u16x4*)(pw + lr * 64 + (((tt * 2 + (lg >> 1)) ^ sw) << 3) +       \
                  ((lg & 1) << 2)) = pb;                                    \
      }                                                                     \
      bf16x8 pa0 = *(const bf16x8*)(pw + lr * 64 + ((lg ^ sw) << 3));       \
      bf16x8 pa1 = *(const bf16x8*)(pw + lr * 64 + (((lg + 4) ^ sw) << 3)); \
      _Pragma("unroll") for (int d = 0; d < 4; d++) {                       \
        const u16* vr = vc + (d * 16 + lr) * 128 + (h2 << 6);               \
        bf16x8 v0 = *(const bf16x8*)(vr + ((lg ^ sw) << 3));                \
        bf16x8 v1 = *(const bf16x8*)(vr + (((lg + 4) ^ sw) << 3));          \
        ctxacc[d] = MFMA16(pa0, v0, ctxacc[d]);                             \
        ctxacc[d] = MFMA16(pa1, v1, ctxacc[d]);                             \
      }                                                                     \
    }                                                                       \
  }
#endif

  mA = *(const uint4*)(mrow);
  STAGE_K(0, 0);
  STAGE_V(0, 0);
  for (int it = 0; it < 7; it++) {
    int kt = it * 2;
    mB = *(const uint4*)(mrow + (kt + 1) * 4);
    STAGE_K(1, kt + 1);
    STAGE_V(1, kt + 1);
    WAITCNT(5);
    BAR();
    P1_BODY(0, mA, kt);
    BAR();
    mA = *(const uint4*)(mrow + (kt + 2) * 4);
    STAGE_K(0, kt + 2);
    STAGE_V(0, kt + 2);
    WAITCNT(5);
    BAR();
    P1_BODY(1, mB, kt + 1);
    BAR();
  }
  // kt = 14
  mB = *(const uint4*)(mrow + 15 * 4);
  STAGE_K(1, 15);
  STAGE_V(1, 15);
  WAITCNT(5);
  BAR();
  P1_BODY(0, mA, 14);
  BAR();
  // kt = 15
  WAITCNT(8);  // retire stage15+mask15 (oldest); leave prev tile's 8 attn stores
  BAR();
  P1_BODY(1, mB, 15);

  // context out: [B,S,H,DH] == [M_TOK, D_MODEL] row-major
#pragma unroll
  for (int d = 0; d < 4; d++)
#pragma unroll
    for (int r = 0; r < 4; r++) {
      int sq = q0 + w * 16 + lg * 4 + r;
      ctx[(size_t)(b * S_LEN + sq) * D_MODEL + h * D_HEAD + d * 16 + lr] = f2bf(ctxacc[d][r]);
    }
#undef STAGE_K
#undef STAGE_V
#undef P0_BODY
#undef P1_BODY
}

// ---------------- workspace layout (u16 units) ----------------
#define O_KBF 0u          // bf16 key input; reused for packed mask after projections
#define O_VBF 4194304u
#define O_QBF 8388608u
#define O_WQ 12582912u
#define O_WK 13631488u
#define O_WV 14680064u
#define O_WO 15728640u
#define O_QUP 16777216u
#define O_KUP 20971520u
#define O_VUP 25165824u   // V head-transposed [b][h][dh][s]
#define O_CTX 29360128u
// total = 33554432 u16 = 64 MiB

extern "C" void kernel_launch(void* const* d_in, const int* in_sizes, int n_in,
                              void* d_out, int out_size, void* d_ws, size_t ws_size,
                              hipStream_t stream) {
  const float* key = (const float*)d_in[0];
  const float* value = (const float*)d_in[1];
  const float* query = (const float*)d_in[2];
  const int* mask = (const int*)d_in[3];
  const float* Wq = (const float*)d_in[4];
  const float* bq = (const float*)d_in[5];
  const float* Wk = (const float*)d_in[6];
  const float* bk = (const float*)d_in[7];
  const float* Wv = (const float*)d_in[8];
  const float* bv = (const float*)d_in[9];
  const float* Wo = (const float*)d_in[10];
  const float* bo = (const float*)d_in[11];

  u16* ws = (u16*)d_ws;
  u16* kbf = ws + O_KBF;
  u16* vbf = ws + O_VBF;
  u16* qbf = ws + O_QBF;
  u16* wqb = ws + O_WQ;
  u16* wkb = ws + O_WK;
  u16* wvb = ws + O_WV;
  u16* wob = ws + O_WO;
  u16* qup = ws + O_QUP;
  u16* kup = ws + O_KUP;
  u16* vtg = ws + O_VUP;
  u16* ctxb = ws + O_CTX;

  float* out = (float*)d_out;
  float* attn = out + (size_t)N_BATCH * S_LEN * D_MODEL;

  cvt7_kernel<<<dim3(512, 7), 256, 0, stream>>>(key, value, query, Wq, Wk, Wv, Wo, kbf, vbf, qbf,
                                                wqb, wkb, wvb, wob);
  proj3_kernel<<<dim3(32, 8, 3), 256, 0, stream>>>(kbf, vbf, qbf, wkb, wvb, wqb, bk, bv, bq, kup,
                                                   vtg, qup);
  pack_mask<<<1024, 256, 0, stream>>>(mask, (unsigned long long*)kbf);
  attn_kernel<<<512, 512, 0, stream>>>(qup, kup, vtg, (const u32*)kbf, attn, ctxb);
  gemm_out_kernel<<<dim3(32, 8), 256, 0, stream>>>(ctxb, wob, bo, out);
}